// Round 2
// baseline (162.897 us; speedup 1.0000x reference)
//
#include <hip/hip_runtime.h>
#include <math.h>

#define DD 32
#define MM 16

// ---------- helpers ----------
__device__ __forceinline__ float rsum8(float v) {
    // sum across the 8-lane group (lanes differ only in bits 0..2)
    v += __shfl_xor(v, 1);
    v += __shfl_xor(v, 2);
    v += __shfl_xor(v, 4);
    return v;
}

// ---------- kernel 1: per-item precompute, 8 threads per item ----------
// tbl[i*40 + 0..31]  = t_i[d] = sum_e W_bil[d][e] * item_e[i][e]
// tbl[i*40 + 32..39] = c_i[j] = sum_d W1[j][64+d] * item_e[i][d]
__global__ void precompute_item8(const float* __restrict__ item_table,
                                 const float* __restrict__ W_bil,
                                 const float* __restrict__ W1,
                                 float* __restrict__ tbl, int NI) {
    int gid = blockIdx.x * blockDim.x + threadIdx.x;
    int i = gid >> 3, l = gid & 7;
    if (i >= NI) return;
    float4 it[8];
    const float4* q = (const float4*)(item_table + (size_t)i * DD);
#pragma unroll
    for (int k = 0; k < 8; ++k) it[k] = q[k];
    float tt[4];
#pragma unroll
    for (int r = 0; r < 4; ++r) {
        const float4* w = (const float4*)(W_bil + (size_t)(4 * l + r) * DD);
        float s = 0.f;
#pragma unroll
        for (int k = 0; k < 8; ++k) {
            float4 wv = w[k];
            s = fmaf(wv.x, it[k].x, s);
            s = fmaf(wv.y, it[k].y, s);
            s = fmaf(wv.z, it[k].z, s);
            s = fmaf(wv.w, it[k].w, s);
        }
        tt[r] = s;
    }
    float cj = 0.f;
    const float4* w1 = (const float4*)(W1 + l * 96 + 64);
#pragma unroll
    for (int k = 0; k < 8; ++k) {
        float4 wv = w1[k];
        cj = fmaf(wv.x, it[k].x, cj);
        cj = fmaf(wv.y, it[k].y, cj);
        cj = fmaf(wv.z, it[k].z, cj);
        cj = fmaf(wv.w, it[k].w, cj);
    }
    float* o = tbl + (size_t)i * 40;
    *(float4*)(o + 4 * l) = make_float4(tt[0], tt[1], tt[2], tt[3]);
    o[32 + l] = cj;
}

// ---------- kernel 2: main, 8 lanes per row, each lane owns 4 dims ----------
template <bool USE_TBL>
__global__ void bilinear_main8(const int* __restrict__ item_inputs,
                               const int* __restrict__ member_ids,
                               const unsigned char* __restrict__ member_mask,
                               const float* __restrict__ user_table,
                               const float* __restrict__ item_table,
                               const float* __restrict__ tbl,
                               const float* __restrict__ W_bil,
                               const float* __restrict__ b_bil,
                               const float* __restrict__ W1,
                               const float* __restrict__ b1,
                               const float* __restrict__ W2,
                               const float* __restrict__ b2,
                               float* __restrict__ out, int Btot) {
    int gid = blockIdx.x * blockDim.x + threadIdx.x;
    int b = gid >> 3;                 // row
    int l = threadIdx.x & 7;          // dim-group lane (owns dims 4l..4l+3)
    if (b >= Btot) return;
    int laneBase = (threadIdx.x & 63) & 56;  // wave-lane base of the 8-group

    int item = item_inputs[b];        // same address across the 8-group

    // prefix mask -> length (all 8 lanes load the same 16B; L1 broadcast)
    uint4 mv = *(const uint4*)(member_mask + (size_t)b * MM);
    int len = __popc(mv.x & 0x01010101u) + __popc(mv.y & 0x01010101u) +
              __popc(mv.z & 0x01010101u) + __popc(mv.w & 0x01010101u);

    // lane l holds member ids {2l, 2l+1}
    int2 id2 = ((const int2*)(member_ids + (size_t)b * MM))[l];

    float4 t4;     // this lane's 4 dims of t = W_bil * item_e
    float  cjl;    // item-only MLP partial for j == l
    if (USE_TBL) {
        const float* tb = tbl + (size_t)item * 40;
        t4  = *(const float4*)(tb + 4 * l);
        cjl = tb[32 + l];
    } else {
        float4 it[8];
        const float4* q = (const float4*)(item_table + (size_t)item * DD);
#pragma unroll
        for (int k = 0; k < 8; ++k) it[k] = q[k];
        float tt[4];
#pragma unroll
        for (int r = 0; r < 4; ++r) {
            const float4* w = (const float4*)(W_bil + (size_t)(4 * l + r) * DD);
            float s = 0.f;
#pragma unroll
            for (int k = 0; k < 8; ++k) {
                float4 wv = w[k];
                s = fmaf(wv.x, it[k].x, s); s = fmaf(wv.y, it[k].y, s);
                s = fmaf(wv.z, it[k].z, s); s = fmaf(wv.w, it[k].w, s);
            }
            tt[r] = s;
        }
        t4 = make_float4(tt[0], tt[1], tt[2], tt[3]);
        cjl = 0.f;
        const float4* w1 = (const float4*)(W1 + l * 96 + 64);
#pragma unroll
        for (int k = 0; k < 8; ++k) {
            float4 wv = w1[k];
            cjl = fmaf(wv.x, it[k].x, cjl); cjl = fmaf(wv.y, it[k].y, cjl);
            cjl = fmaf(wv.z, it[k].z, cjl); cjl = fmaf(wv.w, it[k].w, cjl);
        }
    }

    float bb = b_bil[0];
    float4 fin = make_float4(0.f, 0.f, 0.f, 0.f);

    // members in chunks of 4: 4 gathers in flight, group-uniform early exit
    for (int c = 0; c < 4; ++c) {
        int m0 = 4 * c;
        if (m0 >= len) break;
        int sA = laneBase | (2 * c);
        int sB = laneBase | (2 * c + 1);
        int ida = __shfl(id2.x, sA);   // member m0
        int idb = __shfl(id2.y, sA);   // member m0+1
        int idc = __shfl(id2.x, sB);   // member m0+2
        int idd = __shfl(id2.y, sB);   // member m0+3
        float4 ma = *(const float4*)(user_table + (size_t)ida * DD + 4 * l);
        float4 mb = *(const float4*)(user_table + (size_t)idb * DD + 4 * l);
        float4 mc = *(const float4*)(user_table + (size_t)idc * DD + 4 * l);
        float4 md = *(const float4*)(user_table + (size_t)idd * DD + 4 * l);

        float pa = ma.x * t4.x; pa = fmaf(ma.y, t4.y, pa); pa = fmaf(ma.z, t4.z, pa); pa = fmaf(ma.w, t4.w, pa);
        float pb = mb.x * t4.x; pb = fmaf(mb.y, t4.y, pb); pb = fmaf(mb.z, t4.z, pb); pb = fmaf(mb.w, t4.w, pb);
        float pc = mc.x * t4.x; pc = fmaf(mc.y, t4.y, pc); pc = fmaf(mc.z, t4.z, pc); pc = fmaf(mc.w, t4.w, pc);
        float pd = md.x * t4.x; pd = fmaf(md.y, t4.y, pd); pd = fmaf(md.z, t4.z, pd); pd = fmaf(md.w, t4.w, pd);
        pa = rsum8(pa); pb = rsum8(pb); pc = rsum8(pc); pd = rsum8(pd);
        float sa = (m0 + 0 < len) ? (pa + bb) : 0.f;
        float sb = (m0 + 1 < len) ? (pb + bb) : 0.f;
        float sc = (m0 + 2 < len) ? (pc + bb) : 0.f;
        float sd = (m0 + 3 < len) ? (pd + bb) : 0.f;
        fin.x = fmaf(sa, ma.x, fin.x); fin.y = fmaf(sa, ma.y, fin.y);
        fin.z = fmaf(sa, ma.z, fin.z); fin.w = fmaf(sa, ma.w, fin.w);
        fin.x = fmaf(sb, mb.x, fin.x); fin.y = fmaf(sb, mb.y, fin.y);
        fin.z = fmaf(sb, mb.z, fin.z); fin.w = fmaf(sb, mb.w, fin.w);
        fin.x = fmaf(sc, mc.x, fin.x); fin.y = fmaf(sc, mc.y, fin.y);
        fin.z = fmaf(sc, mc.z, fin.z); fin.w = fmaf(sc, mc.w, fin.w);
        fin.x = fmaf(sd, md.x, fin.x); fin.y = fmaf(sd, md.y, fin.y);
        fin.z = fmaf(sd, md.z, fin.z); fin.w = fmaf(sd, md.w, fin.w);
    }

    // epilogue MLP: h_j = relu(cj_j + b1_j + sum_d W1[j,d]*(f*i)[d] + W1[j,32+d]*f[d])
    float4 iv = *(const float4*)(item_table + (size_t)item * DD + 4 * l);
    float4 p4 = make_float4(fin.x * iv.x, fin.y * iv.y, fin.z * iv.z, fin.w * iv.w);

    float part[8];
#pragma unroll
    for (int j = 0; j < 8; ++j) {
        const float* w = W1 + j * 96;
        float4 wa = *(const float4*)(w + 4 * l);       // W1[j, 4l..]
        float4 wb = *(const float4*)(w + 32 + 4 * l);  // W1[j, 32+4l..]
        float s = wa.x * p4.x;
        s = fmaf(wa.y, p4.y, s); s = fmaf(wa.z, p4.z, s); s = fmaf(wa.w, p4.w, s);
        s = fmaf(wb.x, fin.x, s); s = fmaf(wb.y, fin.y, s);
        s = fmaf(wb.z, fin.z, s); s = fmaf(wb.w, fin.w, s);
        part[j] = s;
    }
    part[l] += cjl + b1[l];   // each lane injects the item partial for j == its own slot

#pragma unroll
    for (int j = 0; j < 8; ++j) part[j] = rsum8(part[j]);

    float z = b2[0];
#pragma unroll
    for (int j = 0; j < 8; ++j) {
        float h = part[j] > 0.f ? part[j] : 0.f;
        z = fmaf(W2[j], h, z);
    }
    if (l == 0) out[b] = 1.f / (1.f + __expf(-z));
}

extern "C" void kernel_launch(void* const* d_in, const int* in_sizes, int n_in,
                              void* d_out, int out_size, void* d_ws, size_t ws_size,
                              hipStream_t stream) {
    const int*           item_inputs = (const int*)d_in[0];
    const int*           member_ids  = (const int*)d_in[1];
    const unsigned char* member_mask = (const unsigned char*)d_in[2];
    const float*         user_table  = (const float*)d_in[3];
    const float*         item_table  = (const float*)d_in[4];
    const float*         W_bil       = (const float*)d_in[5];
    const float*         b_bil       = (const float*)d_in[6];
    const float*         W1          = (const float*)d_in[7];
    const float*         b1          = (const float*)d_in[8];
    const float*         W2          = (const float*)d_in[9];
    const float*         b2          = (const float*)d_in[10];
    float* out = (float*)d_out;

    int Btot = in_sizes[0];
    int NI   = in_sizes[4] / DD;

    bool use_tbl = ws_size >= (size_t)NI * 40 * sizeof(float);
    const int blk = 256;
    int grid_main = (int)(((size_t)Btot * 8 + blk - 1) / blk);
    if (use_tbl) {
        float* tbl = (float*)d_ws;
        int grid_pre = (int)(((size_t)NI * 8 + blk - 1) / blk);
        precompute_item8<<<grid_pre, blk, 0, stream>>>(item_table, W_bil, W1, tbl, NI);
        bilinear_main8<true><<<grid_main, blk, 0, stream>>>(
            item_inputs, member_ids, member_mask, user_table, item_table, tbl,
            W_bil, b_bil, W1, b1, W2, b2, out, Btot);
    } else {
        bilinear_main8<false><<<grid_main, blk, 0, stream>>>(
            item_inputs, member_ids, member_mask, user_table, item_table, nullptr,
            W_bil, b_bil, W1, b1, W2, b2, out, Btot);
    }
}

// Round 5
// 162.674 us; speedup vs baseline: 1.0014x; 1.0014x over previous
//
#include <hip/hip_runtime.h>
#include <math.h>

#define DD 32
#define MM 16

// ---------- helpers ----------
__device__ __forceinline__ void load8f4(const float* __restrict__ p, float* r) {
    const float4* q = (const float4*)p;
#pragma unroll
    for (int i = 0; i < 8; ++i) {
        float4 v = q[i];
        r[4*i+0] = v.x; r[4*i+1] = v.y; r[4*i+2] = v.z; r[4*i+3] = v.w;
    }
}

__device__ __forceinline__ int mask_len(const unsigned char* __restrict__ mp) {
    uint4 mv = *(const uint4*)mp;
    return __popc(mv.x & 0x01010101u) + __popc(mv.y & 0x01010101u) +
           __popc(mv.z & 0x01010101u) + __popc(mv.w & 0x01010101u);
}

// score_m = mem.t + bb ; fin += score_m * mem   (two members: 16 loads in flight)
__device__ __forceinline__ void acc_pair(const float* __restrict__ user_table,
                                         int idA, int idB, const float* __restrict__ t,
                                         float bb, float* __restrict__ fin) {
    float meA[DD], meB[DD];
    load8f4(user_table + (size_t)idA * DD, meA);
    load8f4(user_table + (size_t)idB * DD, meB);
    float sA = bb, sB = bb;
#pragma unroll
    for (int d = 0; d < DD; ++d) sA = fmaf(meA[d], t[d], sA);
#pragma unroll
    for (int d = 0; d < DD; ++d) sB = fmaf(meB[d], t[d], sB);
#pragma unroll
    for (int d = 0; d < DD; ++d) fin[d] = fmaf(sA, meA[d], fin[d]);
#pragma unroll
    for (int d = 0; d < DD; ++d) fin[d] = fmaf(sB, meB[d], fin[d]);
}

__device__ __forceinline__ void acc_one(const float* __restrict__ user_table,
                                        int idA, const float* __restrict__ t,
                                        float bb, float* __restrict__ fin) {
    float meA[DD];
    load8f4(user_table + (size_t)idA * DD, meA);
    float sA = bb;
#pragma unroll
    for (int d = 0; d < DD; ++d) sA = fmaf(meA[d], t[d], sA);
#pragma unroll
    for (int d = 0; d < DD; ++d) fin[d] = fmaf(sA, meA[d], fin[d]);
}

// MLP epilogue: h_j = relu(cj_j + b1_j + sum_d W1[j,d]*(f*i)[d] + W1[j,32+d]*f[d]); y = sigmoid(W2.h + b2)
__device__ __forceinline__ float epilogue(const float* __restrict__ fin,
                                          const float* __restrict__ it,
                                          const float4 c0, const float4 c1,
                                          const float* __restrict__ W1,
                                          const float* __restrict__ b1,
                                          const float* __restrict__ W2,
                                          const float* __restrict__ b2) {
    float h[8] = {c0.x, c0.y, c0.z, c0.w, c1.x, c1.y, c1.z, c1.w};
#pragma unroll
    for (int j = 0; j < 8; ++j) h[j] += b1[j];
#pragma unroll
    for (int d = 0; d < DD; ++d) {
        float f = fin[d];
        float p = f * it[d];
#pragma unroll
        for (int j = 0; j < 8; ++j) {
            h[j] = fmaf(W1[j * 96 + d], p, h[j]);
            h[j] = fmaf(W1[j * 96 + 32 + d], f, h[j]);
        }
    }
    float z = b2[0];
#pragma unroll
    for (int j = 0; j < 8; ++j) {
        float hv = h[j] > 0.f ? h[j] : 0.f;
        z = fmaf(W2[j], hv, z);
    }
    return 1.f / (1.f + __expf(-z));
}

// ---------- kernel 1: per-item precompute, 8 threads/item (proven in R2) ----------
// tbl[i*40 + 0..31] = t_i = W_bil * item_i ; tbl[i*40 + 32..39] = c_i[j] = W1[j,64:96].item_i
__global__ void precompute_item8(const float* __restrict__ item_table,
                                 const float* __restrict__ W_bil,
                                 const float* __restrict__ W1,
                                 float* __restrict__ tbl, int NI) {
    int gid = blockIdx.x * blockDim.x + threadIdx.x;
    int i = gid >> 3, l = gid & 7;
    if (i >= NI) return;
    float4 it[8];
    const float4* q = (const float4*)(item_table + (size_t)i * DD);
#pragma unroll
    for (int k = 0; k < 8; ++k) it[k] = q[k];
    float tt[4];
#pragma unroll
    for (int r = 0; r < 4; ++r) {
        const float4* w = (const float4*)(W_bil + (size_t)(4 * l + r) * DD);
        float s = 0.f;
#pragma unroll
        for (int k = 0; k < 8; ++k) {
            float4 wv = w[k];
            s = fmaf(wv.x, it[k].x, s); s = fmaf(wv.y, it[k].y, s);
            s = fmaf(wv.z, it[k].z, s); s = fmaf(wv.w, it[k].w, s);
        }
        tt[r] = s;
    }
    float cj = 0.f;
    const float4* w1 = (const float4*)(W1 + l * 96 + 64);
#pragma unroll
    for (int k = 0; k < 8; ++k) {
        float4 wv = w1[k];
        cj = fmaf(wv.x, it[k].x, cj); cj = fmaf(wv.y, it[k].y, cj);
        cj = fmaf(wv.z, it[k].z, cj); cj = fmaf(wv.w, it[k].w, cj);
    }
    float* o = tbl + (size_t)i * 40;
    *(float4*)(o + 4 * l) = make_float4(tt[0], tt[1], tt[2], tt[3]);
    o[32 + l] = cj;
}

// ---------- kernel 2: main, 1 thread/row, tbl-based t, paired gathers ----------
__global__ __launch_bounds__(256)
void bilinear_tbl(const int* __restrict__ item_inputs,
                  const int* __restrict__ member_ids,
                  const unsigned char* __restrict__ member_mask,
                  const float* __restrict__ user_table,
                  const float* __restrict__ item_table,
                  const float* __restrict__ tbl,
                  const float* __restrict__ b_bil,
                  const float* __restrict__ W1,
                  const float* __restrict__ b1,
                  const float* __restrict__ W2,
                  const float* __restrict__ b2,
                  float* __restrict__ out, int Btot) {
    int b = blockIdx.x * blockDim.x + threadIdx.x;
    if (b >= Btot) return;
    int item = item_inputs[b];
    int len = mask_len(member_mask + (size_t)b * MM);

    // hoist all member ids (64B contiguous) so address math is ready early
    const int4* idp = (const int4*)(member_ids + (size_t)b * MM);
    int4 iv0 = idp[0], iv1 = idp[1], iv2 = idp[2], iv3 = idp[3];

    const float* tb = tbl + (size_t)item * 40;
    float t[DD];
    load8f4(tb, t);
    float bb = b_bil[0];

    float fin[DD];
#pragma unroll
    for (int d = 0; d < DD; ++d) fin[d] = 0.f;

    // len >= 1 always. Paired processing: 16 loads in flight per exposure.
    if (len >= 2) acc_pair(user_table, iv0.x, iv0.y, t, bb, fin);
    else          acc_one (user_table, iv0.x, t, bb, fin);
    if (len >= 4)       acc_pair(user_table, iv0.z, iv0.w, t, bb, fin);
    else if (len == 3)  acc_one (user_table, iv0.z, t, bb, fin);
    if (len >= 6)       acc_pair(user_table, iv1.x, iv1.y, t, bb, fin);
    else if (len == 5)  acc_one (user_table, iv1.x, t, bb, fin);
    if (len >= 8)       acc_pair(user_table, iv1.z, iv1.w, t, bb, fin);
    else if (len == 7)  acc_one (user_table, iv1.z, t, bb, fin);
    if (len >= 10)      acc_pair(user_table, iv2.x, iv2.y, t, bb, fin);
    else if (len == 9)  acc_one (user_table, iv2.x, t, bb, fin);
    if (len >= 12)      acc_pair(user_table, iv2.z, iv2.w, t, bb, fin);
    else if (len == 11) acc_one (user_table, iv2.z, t, bb, fin);
    if (len >= 14)      acc_pair(user_table, iv3.x, iv3.y, t, bb, fin);
    else if (len == 13) acc_one (user_table, iv3.x, t, bb, fin);
    if (len >= 16)      acc_pair(user_table, iv3.z, iv3.w, t, bb, fin);
    else if (len == 15) acc_one (user_table, iv3.z, t, bb, fin);

    float it[DD];
    load8f4(item_table + (size_t)item * DD, it);
    float4 c0 = *(const float4*)(tb + 32);
    float4 c1 = *(const float4*)(tb + 36);
    out[b] = epilogue(fin, it, c0, c1, W1, b1, W2, b2);
}

// ---------- fallback (ws too small): flat 1 thread/row, inline t ----------
__global__ void bilinear_flat(const int* __restrict__ item_inputs,
                              const int* __restrict__ member_ids,
                              const unsigned char* __restrict__ member_mask,
                              const float* __restrict__ user_table,
                              const float* __restrict__ item_table,
                              const float* __restrict__ W_bil,
                              const float* __restrict__ b_bil,
                              const float* __restrict__ W1,
                              const float* __restrict__ b1,
                              const float* __restrict__ W2,
                              const float* __restrict__ b2,
                              float* __restrict__ out, int Btot) {
    int b = blockIdx.x * blockDim.x + threadIdx.x;
    if (b >= Btot) return;
    int item = item_inputs[b];
    int len = mask_len(member_mask + (size_t)b * MM);
    float it0[DD];
    load8f4(item_table + (size_t)item * DD, it0);
    float t[DD];
#pragma unroll 4
    for (int d = 0; d < DD; ++d) {
        float s = 0.f;
#pragma unroll
        for (int e = 0; e < DD; ++e) s = fmaf(W_bil[d * DD + e], it0[e], s);
        t[d] = s;
    }
    float cj[8];
#pragma unroll
    for (int j = 0; j < 8; ++j) {
        float s = 0.f;
#pragma unroll
        for (int d = 0; d < DD; ++d) s = fmaf(W1[j * 96 + 64 + d], it0[d], s);
        cj[j] = s;
    }
    const int4* idp = (const int4*)(member_ids + (size_t)b * MM);
    float bb = b_bil[0];
    float fin[DD];
#pragma unroll
    for (int d = 0; d < DD; ++d) fin[d] = 0.f;
#pragma unroll 1
    for (int c = 0; c < 4; ++c) {
        int m0 = 4 * c;
        if (m0 >= len) break;
        int4 iv = idp[c];
        int rem = len - m0;
        if (rem >= 2) acc_pair(user_table, iv.x, iv.y, t, bb, fin);
        else          acc_one(user_table, iv.x, t, bb, fin);
        if (rem >= 4)      acc_pair(user_table, iv.z, iv.w, t, bb, fin);
        else if (rem == 3) acc_one(user_table, iv.z, t, bb, fin);
    }
    float4 c0 = make_float4(cj[0], cj[1], cj[2], cj[3]);
    float4 c1 = make_float4(cj[4], cj[5], cj[6], cj[7]);
    out[b] = epilogue(fin, it0, c0, c1, W1, b1, W2, b2);
}

extern "C" void kernel_launch(void* const* d_in, const int* in_sizes, int n_in,
                              void* d_out, int out_size, void* d_ws, size_t ws_size,
                              hipStream_t stream) {
    const int*           item_inputs = (const int*)d_in[0];
    const int*           member_ids  = (const int*)d_in[1];
    const unsigned char* member_mask = (const unsigned char*)d_in[2];
    const float*         user_table  = (const float*)d_in[3];
    const float*         item_table  = (const float*)d_in[4];
    const float*         W_bil       = (const float*)d_in[5];
    const float*         b_bil       = (const float*)d_in[6];
    const float*         W1          = (const float*)d_in[7];
    const float*         b1          = (const float*)d_in[8];
    const float*         W2          = (const float*)d_in[9];
    const float*         b2          = (const float*)d_in[10];
    float* out = (float*)d_out;

    int Btot = in_sizes[0];
    int NI   = in_sizes[4] / DD;

    size_t tbl_bytes = (size_t)NI * 40 * sizeof(float);
    const int blk = 256;
    if (ws_size >= tbl_bytes) {
        float* tbl = (float*)d_ws;
        int grid_pre = (int)(((size_t)NI * 8 + blk - 1) / blk);
        precompute_item8<<<grid_pre, blk, 0, stream>>>(item_table, W_bil, W1, tbl, NI);
        bilinear_tbl<<<(Btot + blk - 1) / blk, blk, 0, stream>>>(
            item_inputs, member_ids, member_mask, user_table, item_table, tbl,
            b_bil, W1, b1, W2, b2, out, Btot);
    } else {
        bilinear_flat<<<(Btot + blk - 1) / blk, blk, 0, stream>>>(
            item_inputs, member_ids, member_mask, user_table, item_table,
            W_bil, b_bil, W1, b1, W2, b2, out, Btot);
    }
}